// Round 4
// baseline (369.523 us; speedup 1.0000x reference)
//
#include <hip/hip_runtime.h>
#include <cstdint>

#define SEQ 2048
#define ED  2048
#define NHEADS 32
#define NKV 8
#define HD 64
#define KVD 512   // NKV*HD

typedef __attribute__((ext_vector_type(8))) short short8;
typedef __attribute__((ext_vector_type(8))) unsigned short ushort8;
typedef __attribute__((ext_vector_type(4))) float f32x4;

__device__ __forceinline__ float bf2f(unsigned short u){ return __uint_as_float(((unsigned)u)<<16); }
__device__ __forceinline__ unsigned short f2bf(float f){
  unsigned x = __float_as_uint(f);
  return (unsigned short)((x + 0x7fffu + ((x>>16)&1u)) >> 16);
}

__device__ __forceinline__ void gld_lds16(const void* g, void* l){
  __builtin_amdgcn_global_load_lds((const __attribute__((address_space(1))) unsigned*)g,
                                   (__attribute__((address_space(3))) unsigned*)l, 16, 0, 0);
}

// ---------------- fused fp32 -> bf16 convert for all 6 tensors ----------------
__global__ __launch_bounds__(256) void cvt_all(const float* __restrict__ Xq, const float* __restrict__ Xkv,
                                               const float* __restrict__ wq, const float* __restrict__ wk,
                                               const float* __restrict__ wv, const float* __restrict__ wo,
                                               unsigned short* __restrict__ Xb, unsigned short* __restrict__ KVb,
                                               unsigned short* __restrict__ Wqb, unsigned short* __restrict__ WKVb,
                                               unsigned short* __restrict__ Wob){
  int b = blockIdx.x;
  const float* src; unsigned short* dst;
  if (b < 2048)      { src = Xq;  dst = Xb; }
  else if (b < 4096) { src = Xkv; dst = KVb;  b -= 2048; }
  else if (b < 6144) { src = wq;  dst = Wqb;  b -= 4096; }
  else if (b < 6656) { src = wk;  dst = WKVb; b -= 6144; }
  else if (b < 7168) { src = wv;  dst = WKVb + (size_t)512*ED; b -= 6656; }
  else               { src = wo;  dst = Wob;  b -= 7168; }
  size_t t = (size_t)b*256 + threadIdx.x;
  const f32x4* p = (const f32x4*)src + t*2;
  f32x4 a = p[0], c = p[1];
  ushort8 o;
  o[0]=f2bf(a[0]); o[1]=f2bf(a[1]); o[2]=f2bf(a[2]); o[3]=f2bf(a[3]);
  o[4]=f2bf(c[0]); o[5]=f2bf(c[1]); o[6]=f2bf(c[2]); o[7]=f2bf(c[3]);
  *(ushort8*)(dst + t*8) = o;
}

// ---------------- fused split-K reduce (fp32 read) + RoPE + bf16 write ----------------
// b<2048: Q rope; b<2560: K rope; else: V plain cvt
__global__ __launch_bounds__(256) void rope_cvt(const float* __restrict__ Qf, const float* __restrict__ Kf,
                                                const float* __restrict__ Vtf,
                                                unsigned short* __restrict__ Qb, unsigned short* __restrict__ Kb,
                                                unsigned short* __restrict__ Vtb,
                                                const float* __restrict__ cq, const float* __restrict__ sq,
                                                const float* __restrict__ ck, const float* __restrict__ sk){
  int b = blockIdx.x;
  if (b >= 2560){ // V: plain fp32->bf16 copy (interleave already applied at write)
    size_t t = (size_t)(b-2560)*256 + threadIdx.x;
    const f32x4* p = (const f32x4*)Vtf + t*2;
    f32x4 a = p[0], c = p[1];
    ushort8 o;
    o[0]=f2bf(a[0]); o[1]=f2bf(a[1]); o[2]=f2bf(a[2]); o[3]=f2bf(a[3]);
    o[4]=f2bf(c[0]); o[5]=f2bf(c[1]); o[6]=f2bf(c[2]); o[7]=f2bf(c[3]);
    *(ushort8*)(Vtb + t*8) = o;
    return;
  }
  const float* src; unsigned short* dst; const float* cosT; const float* sinT; int lw; float scale;
  if (b < 2048){ src=Qf; dst=Qb; cosT=cq; sinT=sq; lw=11; scale=0.125f*1.44269504088896f; }
  else { b -= 2048; src=Kf; dst=Kb; cosT=ck; sinT=sk; lw=9; scale=1.0f; }
  int t = b*256 + threadIdx.x;
  int e = t*8;
  int s = e >> lw;
  int col = e & ((1<<lw)-1);
  int i0 = (col & 63) >> 1;
  const f32x4* p = (const f32x4*)(src + e);
  f32x4 x0 = p[0], x1 = p[1];
  f32x4 c  = *(const f32x4*)(cosT + s*32 + i0);
  f32x4 sn = *(const f32x4*)(sinT + s*32 + i0);
  ushort8 o;
  float xs[8] = {x0[0],x0[1],x0[2],x0[3],x1[0],x1[1],x1[2],x1[3]};
#pragma unroll
  for(int q=0;q<4;q++){
    float a1 = xs[2*q], a2 = xs[2*q+1];
    o[2*q]   = f2bf((a1*c[q] - a2*sn[q])*scale);
    o[2*q+1] = f2bf((a1*sn[q] + a2*c[q])*scale);
  }
  *(ushort8*)(dst + e) = o;
}

// ---------------- 2-phase double-buffered bf16 GEMM body, split-K, atomic fp32 epilogue ----------------
// C[m][n] += sum_{k in half ksplit} A[m*K+k]*B[n*K+k]
// EPI 10: unsafeAtomicAdd fp32 [M][N] into C
// EPI 13: n<512 -> K fp32 [M][512] into C; n>=512 -> V^T key-interleaved fp32 [512][SEQ] into C2
template<int EPI>
__device__ __forceinline__ void gemm_body(const unsigned short* __restrict__ A,
                                          const unsigned short* __restrict__ B,
                                          float* __restrict__ C, float* __restrict__ C2,
                                          int M, int N, int K, int bx, int by, int ksplit,
                                          unsigned short* As, unsigned short* Bs){
  const int tid = threadIdx.x;
  const int lane = tid & 63;
  const int wave = tid >> 6;
  const int wr = wave >> 1, wc = wave & 1;
  const int m0 = by * 128, n0 = bx * 128;
  const int l15 = lane & 15, l4 = lane >> 4;
  const int kbase = ksplit * (K >> 1);

  f32x4 acc[4][4] = {};

  const int arow0 = tid>>2,        sc0 = tid&3, oc0 = sc0 ^ (arow0 & 3);
  const int arow1 = (tid+256)>>2,  oc1 = sc0 ^ (arow1 & 3);
  const unsigned short* Ag0 = A + (size_t)(m0+arow0)*K + kbase + oc0*8;
  const unsigned short* Ag1 = A + (size_t)(m0+arow1)*K + kbase + oc1*8;
  const unsigned short* Bg0 = B + (size_t)(n0+arow0)*K + kbase + oc0*8;
  const unsigned short* Bg1 = B + (size_t)(n0+arow1)*K + kbase + oc1*8;

  const int nk = K >> 6;   // half-K in steps of 32
  gld_lds16(Ag0, As + tid*8);
  gld_lds16(Ag1, As + (tid+256)*8);
  gld_lds16(Bg0, Bs + tid*8);
  gld_lds16(Bg1, Bs + (tid+256)*8);
  __syncthreads();

  for(int kt=0; kt<nk; kt++){
    const int cur = (kt&1)*4096;
    if (kt+1 < nk){
      const int nxt = cur ^ 4096;
      const int ko = (kt+1)*32;
      gld_lds16(Ag0 + ko, As + nxt + tid*8);
      gld_lds16(Ag1 + ko, As + nxt + (tid+256)*8);
      gld_lds16(Bg0 + ko, Bs + nxt + tid*8);
      gld_lds16(Bg1 + ko, Bs + nxt + (tid+256)*8);
    }
    short8 af[4], bfr[4];
#pragma unroll
    for(int m=0;m<4;m++){
      int row = wr*64 + m*16 + l15;
      af[m] = *(const short8*)&As[cur + row*32 + ((l4 ^ (row&3))*8)];
    }
#pragma unroll
    for(int n=0;n<4;n++){
      int row = wc*64 + n*16 + l15;
      bfr[n] = *(const short8*)&Bs[cur + row*32 + ((l4 ^ (row&3))*8)];
    }
#pragma unroll
    for(int m=0;m<4;m++)
#pragma unroll
      for(int n=0;n<4;n++)
        acc[m][n] = __builtin_amdgcn_mfma_f32_16x16x32_bf16(af[m], bfr[n], acc[m][n], 0,0,0);
    __syncthreads();
  }

#pragma unroll
  for(int m=0;m<4;m++){
    const int row0 = m0 + wr*64 + m*16 + l4*4;
#pragma unroll
    for(int n=0;n<4;n++){
      const int col = n0 + wc*64 + n*16 + l15;
      if constexpr (EPI == 10){
#pragma unroll
        for(int r=0;r<4;r++) unsafeAtomicAdd(&C[(size_t)(row0+r)*N + col], acc[m][n][r]);
      } else { // EPI == 13
        if (n0 < 512){
#pragma unroll
          for(int r=0;r<4;r++) unsafeAtomicAdd(&C[(size_t)(row0+r)*512 + col], acc[m][n][r]);
        } else {
          const int d = col - 512;
#pragma unroll
          for(int r=0;r<4;r++){
            int seq = row0 + r;
            int pos = ((seq>>5)&1)*32 + (seq&15)*2 + ((seq>>4)&1);
            unsafeAtomicAdd(&C2[(size_t)d*SEQ + (seq & ~63) + pos], acc[m][n][r]);
          }
        }
      }
    }
  }
}

// Q-proj (blocks 0..511, split-K=2) + KV-proj (blocks 512..767, split-K=2)
__global__ __launch_bounds__(256) void gemm_proj(const unsigned short* __restrict__ Xb,
                                                 const unsigned short* __restrict__ Wqb,
                                                 const unsigned short* __restrict__ KVb,
                                                 const unsigned short* __restrict__ WKVb,
                                                 float* __restrict__ Qf,
                                                 float* __restrict__ Kf,
                                                 float* __restrict__ Vtf){
  __shared__ unsigned short As[2*128*32];
  __shared__ unsigned short Bs[2*128*32];
  int b = blockIdx.x;
  if (b < 512){
    int s = b>>8, rem = b & 255;
    gemm_body<10>(Xb, Wqb, Qf, nullptr, SEQ, ED, ED, rem&15, rem>>4, s, As, Bs);
  } else {
    int bb = b - 512;
    int s = bb>>7, rem = bb & 127;
    gemm_body<13>(KVb, WKVb, Kf, Vtf, SEQ, 1024, ED, rem&7, rem>>3, s, As, Bs);
  }
}

__global__ __launch_bounds__(256) void gemm_out_k(const unsigned short* __restrict__ Obf,
                                                  const unsigned short* __restrict__ Wob,
                                                  float* __restrict__ out){
  __shared__ unsigned short As[2*128*32];
  __shared__ unsigned short Bs[2*128*32];
  int b = blockIdx.x;
  int s = b>>8, rem = b & 255;
  gemm_body<10>(Obf, Wob, out, nullptr, SEQ, ED, ED, rem&15, rem>>4, s, As, Bs);
}

// ---------------- flash attention: 128 q-rows/block (32/wave), 2-phase K/V, packed P ----------------
__global__ __launch_bounds__(256) void attn_k(const unsigned short* __restrict__ Qb,
                                              const unsigned short* __restrict__ Kb,
                                              const unsigned short* __restrict__ Vt,
                                              unsigned short* __restrict__ Ob){
  __shared__ unsigned short Ks[2][4096];
  __shared__ unsigned short Vs[2][4096];
  __shared__ unsigned Psu[4][1024];          // per-wave: 32 rows x 32 u32 words
  const int tid = threadIdx.x, lane = tid & 63, w = tid >> 6;
  const int l15 = lane & 15, l4 = lane >> 4;
  const int qb = blockIdx.x, h = blockIdx.y, kvh = h & 7;

  const int row = tid>>3, sc = tid&7, oc = sc ^ (row&7);
  const int row2 = row + 32, oc2 = sc ^ (row2&7);
  const unsigned short* Kg0 = Kb + (size_t)row*KVD  + kvh*HD + oc*8;
  const unsigned short* Kg1 = Kb + (size_t)row2*KVD + kvh*HD + oc2*8;
  const unsigned short* Vg0 = Vt + (size_t)(kvh*HD+row)*SEQ  + oc*8;
  const unsigned short* Vg1 = Vt + (size_t)(kvh*HD+row2)*SEQ + oc2*8;

#define ATTN_STAGE(buf, kb_) { \
    const size_t koff = (size_t)(kb_)*64*KVD; const int voff = (kb_)*64; \
    gld_lds16(Kg0 + koff, &Ks[buf][tid*8]); \
    gld_lds16(Kg1 + koff, &Ks[buf][(tid+256)*8]); \
    gld_lds16(Vg0 + voff, &Vs[buf][tid*8]); \
    gld_lds16(Vg1 + voff, &Vs[buf][(tid+256)*8]); }

  ATTN_STAGE(0, 0);

  // Q fragments: 2 m-tiles x 2 k-chunks, straight from global
  short8 qa[2][2];
  {
    const unsigned short* qp0 = Qb + (size_t)(qb*128 + w*32 + l15)*ED + h*HD + l4*8;
    qa[0][0] = *(const short8*)qp0;
    qa[0][1] = *(const short8*)(qp0 + 32);
    const unsigned short* qp1 = qp0 + (size_t)16*ED;
    qa[1][0] = *(const short8*)qp1;
    qa[1][1] = *(const short8*)(qp1 + 32);
  }

  unsigned* Pw = &Psu[w][0];
  f32x4 o_acc[2][4] = {};
  float l_acc[2][4] = {{0.f,0.f,0.f,0.f},{0.f,0.f,0.f,0.f}};
  __syncthreads();

  for(int kb=0; kb<SEQ/64; kb++){
    const int cur = kb & 1;
    if (kb+1 < SEQ/64) ATTN_STAGE(cur^1, kb+1);

    __builtin_amdgcn_s_setprio(1);
    f32x4 s_acc[2][4] = {};
#pragma unroll
    for(int n=0;n<4;n++){
      int key = n*16 + l15;
#pragma unroll
      for(int ks=0;ks<2;ks++){
        short8 kf = *(const short8*)&Ks[cur][key*64 + (((ks*4+l4) ^ (key&7))*8)];
        s_acc[0][n] = __builtin_amdgcn_mfma_f32_16x16x32_bf16(qa[0][ks], kf, s_acc[0][n], 0,0,0);
        s_acc[1][n] = __builtin_amdgcn_mfma_f32_16x16x32_bf16(qa[1][ks], kf, s_acc[1][n], 0,0,0);
      }
    }
    __builtin_amdgcn_s_setprio(0);

    // softmax (no max-subtract; scale folded into Q): pack (key, key+16) pairs
#pragma unroll
    for(int mt=0;mt<2;mt++){
#pragma unroll
      for(int r=0;r<4;r++){
        float p0 = exp2f(s_acc[mt][0][r]), p1 = exp2f(s_acc[mt][1][r]);
        float p2 = exp2f(s_acc[mt][2][r]), p3 = exp2f(s_acc[mt][3][r]);
        l_acc[mt][r] += (p0+p1)+(p2+p3);
        unsigned u01, u23;
        asm("v_cvt_pk_bf16_f32 %0, %1, %2" : "=v"(u01) : "v"(p0), "v"(p1));
        asm("v_cvt_pk_bf16_f32 %0, %1, %2" : "=v"(u23) : "v"(p2), "v"(p3));
        const int q32 = mt*16 + l4*4 + r;
        Pw[q32*32 + (((l15>>2)     ^ (q32&7))<<2) + (l15&3)] = u01;
        Pw[q32*32 + (((4+(l15>>2)) ^ (q32&7))<<2) + (l15&3)] = u23;
      }
    }
    asm volatile("s_waitcnt lgkmcnt(0)" ::: "memory");

    __builtin_amdgcn_s_setprio(1);
#pragma unroll
    for(int ks=0;ks<2;ks++){
      short8 pa0 = *(const short8*)&Pw[(l15     )*32 + (((ks*4+l4) ^ (l15&7))<<2)];
      short8 pa1 = *(const short8*)&Pw[(16+l15  )*32 + (((ks*4+l4) ^ (l15&7))<<2)];
#pragma unroll
      for(int n=0;n<4;n++){
        int d = n*16 + l15;
        short8 vf = *(const short8*)&Vs[cur][d*64 + (((ks*4+l4) ^ (d&7))*8)];
        o_acc[0][n] = __builtin_amdgcn_mfma_f32_16x16x32_bf16(pa0, vf, o_acc[0][n], 0,0,0);
        o_acc[1][n] = __builtin_amdgcn_mfma_f32_16x16x32_bf16(pa1, vf, o_acc[1][n], 0,0,0);
      }
    }
    __builtin_amdgcn_s_setprio(0);
    __syncthreads();
  }
#undef ATTN_STAGE

  // epilogue
#pragma unroll
  for(int mt=0;mt<2;mt++)
#pragma unroll
    for(int r=0;r<4;r++){
      float t = l_acc[mt][r];
      t += __shfl_xor(t,1); t += __shfl_xor(t,2); t += __shfl_xor(t,4); t += __shfl_xor(t,8);
      l_acc[mt][r] = 1.0f / t;
    }
#pragma unroll
  for(int mt=0;mt<2;mt++)
#pragma unroll
    for(int n=0;n<4;n++){
      const int col = h*HD + n*16 + l15;
#pragma unroll
      for(int r=0;r<4;r++){
        const int srow = qb*128 + w*32 + mt*16 + l4*4 + r;
        Ob[(size_t)srow*ED + col] = f2bf(o_acc[mt][n][r] * l_acc[mt][r]);
      }
    }
}

extern "C" void kernel_launch(void* const* d_in, const int* in_sizes, int n_in,
                              void* d_out, int out_size, void* d_ws, size_t ws_size,
                              hipStream_t stream) {
  const float* Xq    = (const float*)d_in[0];
  const float* Xkv   = (const float*)d_in[1];
  const float* cos_q = (const float*)d_in[2];
  const float* sin_q = (const float*)d_in[3];
  const float* cos_k = (const float*)d_in[4];
  const float* sin_k = (const float*)d_in[5];
  const float* wq = (const float*)d_in[7];
  const float* wk = (const float*)d_in[8];
  const float* wv = (const float*)d_in[9];
  const float* wo = (const float*)d_in[10];
  float* out = (float*)d_out;

  char* ws = (char*)d_ws;
  const size_t MB = 1u<<20;
  unsigned short* Xb   = (unsigned short*)(ws + 0*MB);   // 8 MB bf16
  unsigned short* KVb  = (unsigned short*)(ws + 8*MB);   // 8 MB
  unsigned short* Wqb  = (unsigned short*)(ws + 16*MB);  // 8 MB
  unsigned short* WKVb = (unsigned short*)(ws + 24*MB);  // 4 MB
  unsigned short* Wob  = (unsigned short*)(ws + 28*MB);  // 8 MB
  float*          Qf   = (float*)(ws + 36*MB);           // 16 MB fp32 (dead after rope_cvt)
  float*          Kf   = (float*)(ws + 52*MB);           // 4 MB fp32
  float*          Vtf  = (float*)(ws + 56*MB);           // 4 MB fp32
  unsigned short* Qb   = (unsigned short*)(ws + 60*MB);  // 8 MB
  unsigned short* Kb   = (unsigned short*)(ws + 68*MB);  // 2 MB
  unsigned short* Vtb  = (unsigned short*)(ws + 70*MB);  // 2 MB
  unsigned short* Obf  = (unsigned short*)(ws + 36*MB);  // 8 MB, aliases Qf (dead by then)

  // zero split-K accumulators (Qf,Kf,Vtf contiguous) and d_out
  hipMemsetAsync(ws + 36*MB, 0, 24*MB, stream);
  hipMemsetAsync(out, 0, (size_t)SEQ*ED*sizeof(float), stream);

  cvt_all<<<9216,256,0,stream>>>(Xq, Xkv, wq, wk, wv, wo, Xb, KVb, Wqb, WKVb, Wob);

  gemm_proj<<<768,256,0,stream>>>(Xb, Wqb, KVb, WKVb, Qf, Kf, Vtf);

  rope_cvt<<<3072,256,0,stream>>>(Qf, Kf, Vtf, Qb, Kb, Vtb, cos_q, sin_q, cos_k, sin_k);

  attn_k<<<dim3(SEQ/128, NHEADS),256,0,stream>>>(Qb, Kb, Vtb, Obf);

  gemm_out_k<<<512,256,0,stream>>>(Obf, Wob, out);
}

// Round 5
// 283.691 us; speedup vs baseline: 1.3026x; 1.3026x over previous
//
#include <hip/hip_runtime.h>
#include <cstdint>

#define SEQ 2048
#define ED  2048
#define NHEADS 32
#define NKV 8
#define HD 64
#define KVD 512   // NKV*HD

typedef __attribute__((ext_vector_type(8))) short short8;
typedef __attribute__((ext_vector_type(8))) unsigned short ushort8;
typedef __attribute__((ext_vector_type(4))) float f32x4;

__device__ __forceinline__ float bf2f(unsigned short u){ return __uint_as_float(((unsigned)u)<<16); }
__device__ __forceinline__ unsigned short f2bf(float f){
  unsigned x = __float_as_uint(f);
  return (unsigned short)((x + 0x7fffu + ((x>>16)&1u)) >> 16);
}

__device__ __forceinline__ void gld_lds16(const void* g, void* l){
  __builtin_amdgcn_global_load_lds((const __attribute__((address_space(1))) unsigned*)g,
                                   (__attribute__((address_space(3))) unsigned*)l, 16, 0, 0);
}

// ---------------- fused fp32 -> bf16 convert for all 6 tensors ----------------
__global__ __launch_bounds__(256) void cvt_all(const float* __restrict__ Xq, const float* __restrict__ Xkv,
                                               const float* __restrict__ wq, const float* __restrict__ wk,
                                               const float* __restrict__ wv, const float* __restrict__ wo,
                                               unsigned short* __restrict__ Xb, unsigned short* __restrict__ KVb,
                                               unsigned short* __restrict__ Wqb, unsigned short* __restrict__ WKVb,
                                               unsigned short* __restrict__ Wob){
  int b = blockIdx.x;
  const float* src; unsigned short* dst;
  if (b < 2048)      { src = Xq;  dst = Xb; }
  else if (b < 4096) { src = Xkv; dst = KVb;  b -= 2048; }
  else if (b < 6144) { src = wq;  dst = Wqb;  b -= 4096; }
  else if (b < 6656) { src = wk;  dst = WKVb; b -= 6144; }
  else if (b < 7168) { src = wv;  dst = WKVb + (size_t)512*ED; b -= 6656; }
  else               { src = wo;  dst = Wob;  b -= 7168; }
  size_t t = (size_t)b*256 + threadIdx.x;
  const f32x4* p = (const f32x4*)src + t*2;
  f32x4 a = p[0], c = p[1];
  ushort8 o;
  o[0]=f2bf(a[0]); o[1]=f2bf(a[1]); o[2]=f2bf(a[2]); o[3]=f2bf(a[3]);
  o[4]=f2bf(c[0]); o[5]=f2bf(c[1]); o[6]=f2bf(c[2]); o[7]=f2bf(c[3]);
  *(ushort8*)(dst + t*8) = o;
}

// ---------------- merged RoPE for Q and K (in-place on bf16) ----------------
__global__ __launch_bounds__(256) void rope_all(unsigned short* __restrict__ Qb, unsigned short* __restrict__ Kbuf,
                                                const float* __restrict__ cq, const float* __restrict__ sq,
                                                const float* __restrict__ ck, const float* __restrict__ sk){
  int b = blockIdx.x;
  unsigned short* buf; const float* cosT; const float* sinT; int lw; float scale;
  if (b < 2048){ buf=Qb; cosT=cq; sinT=sq; lw=11; scale=0.125f*1.44269504088896f; }
  else { b -= 2048; buf=Kbuf; cosT=ck; sinT=sk; lw=9; scale=1.0f; }
  int t = b*256 + threadIdx.x;
  int e = t*8;
  int s = e >> lw;
  int col = e & ((1<<lw)-1);
  int i0 = (col & 63) >> 1;
  ushort8 v = *(ushort8*)(buf + e);
  f32x4 c  = *(const f32x4*)(cosT + s*32 + i0);
  f32x4 sn = *(const f32x4*)(sinT + s*32 + i0);
  ushort8 o;
#pragma unroll
  for(int p=0;p<4;p++){
    float x1 = bf2f(v[2*p]), x2 = bf2f(v[2*p+1]);
    o[2*p]   = f2bf((x1*c[p] - x2*sn[p])*scale);
    o[2*p+1] = f2bf((x1*sn[p] + x2*c[p])*scale);
  }
  *(ushort8*)(buf + e) = o;
}

// ---------------- 3-stage ring, counted-vmcnt bf16 GEMM body ----------------
// C[m][n] = sum_k A[m*K+k]*B[n*K+k]
// EPI 0: bf16 [M][N]; EPI 2: fp32 [M][N];
// EPI 3: n<512 -> K bf16 [M][512]; n>=512 -> V^T key-interleaved bf16 [512][SEQ] into Cout2
// LDS swizzle: slot = chunk ^ ((row>>1)&3): rows 0..7 cover all 8 positions of a
// 128B bank wrap -> 2-way (free); the old (row&3) XOR left a 4-way conflict.
template<int EPI>
__device__ __forceinline__ void gemm_body(const unsigned short* __restrict__ A,
                                          const unsigned short* __restrict__ B,
                                          void* __restrict__ Cout, void* __restrict__ Cout2,
                                          int M, int N, int K, int bx, int by,
                                          unsigned short* As, unsigned short* Bs){
  const int tid = threadIdx.x;
  const int lane = tid & 63;
  const int wave = tid >> 6;
  const int wr = wave >> 1, wc = wave & 1;
  const int m0 = by * 128, n0 = bx * 128;
  const int l15 = lane & 15, l4 = lane >> 4;

  f32x4 acc[4][4] = {};

  const int arow0 = tid>>2,        sc0 = tid&3, oc0 = sc0 ^ ((arow0>>1) & 3);
  const int arow1 = (tid+256)>>2,  oc1 = sc0 ^ ((arow1>>1) & 3);
  const unsigned short* Ag0 = A + (size_t)(m0+arow0)*K + oc0*8;
  const unsigned short* Ag1 = A + (size_t)(m0+arow1)*K + oc1*8;
  const unsigned short* Bg0 = B + (size_t)(n0+arow0)*K + oc0*8;
  const unsigned short* Bg1 = B + (size_t)(n0+arow1)*K + oc1*8;

  const int nk = K >> 5;

#define GSTAGE(buf_, kt_) { \
    const int ko_ = (kt_)*32; const int bo_ = (buf_)*4096; \
    gld_lds16(Ag0 + ko_, As + bo_ + tid*8); \
    gld_lds16(Ag1 + ko_, As + bo_ + (tid+256)*8); \
    gld_lds16(Bg0 + ko_, Bs + bo_ + tid*8); \
    gld_lds16(Bg1 + ko_, Bs + bo_ + (tid+256)*8); }

  GSTAGE(0, 0);
  GSTAGE(1, 1);

  for(int kt=0; kt<nk; kt++){
    // wait for own stage-kt loads (leave the newer stage in flight), then publish
    if (kt+1 == nk) { asm volatile("s_waitcnt vmcnt(0)" ::: "memory"); }
    else            { asm volatile("s_waitcnt vmcnt(4)" ::: "memory"); }
    __builtin_amdgcn_s_barrier();
    __builtin_amdgcn_sched_barrier(0);

    if (kt+2 < nk) GSTAGE((kt+2)%3, kt+2);

    const int cur = (kt%3)*4096;
    short8 af[4], bfr[4];
#pragma unroll
    for(int m=0;m<4;m++){
      int row = wr*64 + m*16 + l15;
      af[m] = *(const short8*)&As[cur + row*32 + ((l4 ^ ((row>>1)&3))*8)];
    }
#pragma unroll
    for(int n=0;n<4;n++){
      int row = wc*64 + n*16 + l15;
      bfr[n] = *(const short8*)&Bs[cur + row*32 + ((l4 ^ ((row>>1)&3))*8)];
    }
    __builtin_amdgcn_s_setprio(1);
#pragma unroll
    for(int m=0;m<4;m++)
#pragma unroll
      for(int n=0;n<4;n++)
        acc[m][n] = __builtin_amdgcn_mfma_f32_16x16x32_bf16(af[m], bfr[n], acc[m][n], 0,0,0);
    __builtin_amdgcn_s_setprio(0);
  }
#undef GSTAGE

#pragma unroll
  for(int m=0;m<4;m++){
    const int row0 = m0 + wr*64 + m*16 + l4*4;
#pragma unroll
    for(int n=0;n<4;n++){
      const int col = n0 + wc*64 + n*16 + l15;
      if constexpr (EPI == 0){
        unsigned short* C = (unsigned short*)Cout;
#pragma unroll
        for(int r=0;r<4;r++) C[(size_t)(row0+r)*N + col] = f2bf(acc[m][n][r]);
      } else if constexpr (EPI == 2){
        float* C = (float*)Cout;
#pragma unroll
        for(int r=0;r<4;r++) C[(size_t)(row0+r)*N + col] = acc[m][n][r];
      } else { // EPI == 3
        if (n0 < 512){
          unsigned short* C = (unsigned short*)Cout;
#pragma unroll
          for(int r=0;r<4;r++) C[(size_t)(row0+r)*512 + col] = f2bf(acc[m][n][r]);
        } else {
          unsigned short* C = (unsigned short*)Cout2;
          const int d = col - 512;
#pragma unroll
          for(int r=0;r<4;r++){
            int seq = row0 + r;
            // key-interleave within each 64-block: key=32ks+p+16s -> pos=32ks+2p+s
            int pos = ((seq>>5)&1)*32 + (seq&15)*2 + ((seq>>4)&1);
            C[(size_t)d*SEQ + (seq & ~63) + pos] = f2bf(acc[m][n][r]);
          }
        }
      }
    }
  }
}

// merged Q-proj (blocks 0..255) + KV-proj (blocks 256..383)
__global__ __launch_bounds__(256) void gemm_proj(const unsigned short* __restrict__ Xb,
                                                 const unsigned short* __restrict__ Wqb,
                                                 const unsigned short* __restrict__ KVb,
                                                 const unsigned short* __restrict__ WKVb,
                                                 unsigned short* __restrict__ Qb,
                                                 unsigned short* __restrict__ Kb,
                                                 unsigned short* __restrict__ Vtb){
  __shared__ unsigned short As[3*4096];
  __shared__ unsigned short Bs[3*4096];
  int b = blockIdx.x;
  if (b < 256){
    gemm_body<0>(Xb, Wqb, Qb, nullptr, SEQ, ED, ED, b&15, b>>4, As, Bs);
  } else {
    int bb = b - 256;
    gemm_body<3>(KVb, WKVb, Kb, Vtb, SEQ, 1024, ED, bb&7, bb>>3, As, Bs);
  }
}

__global__ __launch_bounds__(256) void gemm_out_k(const unsigned short* __restrict__ Obf,
                                                  const unsigned short* __restrict__ Wob,
                                                  float* __restrict__ out){
  __shared__ unsigned short As[3*4096];
  __shared__ unsigned short Bs[3*4096];
  int b = blockIdx.x;
  gemm_body<2>(Obf, Wob, out, nullptr, SEQ, ED, ED, b&15, b>>4, As, Bs);
}

// ---------------- flash attention: 128 q-rows/block (32/wave), 2-phase K/V, packed P ----------------
__global__ __launch_bounds__(256) void attn_k(const unsigned short* __restrict__ Qb,
                                              const unsigned short* __restrict__ Kb,
                                              const unsigned short* __restrict__ Vt,
                                              unsigned short* __restrict__ Ob){
  __shared__ unsigned short Ks[2][4096];
  __shared__ unsigned short Vs[2][4096];
  __shared__ unsigned Psu[4][1024];          // per-wave: 32 rows x 32 u32 words
  const int tid = threadIdx.x, lane = tid & 63, w = tid >> 6;
  const int l15 = lane & 15, l4 = lane >> 4;
  const int qb = blockIdx.x, h = blockIdx.y, kvh = h & 7;

  const int row = tid>>3, sc = tid&7, oc = sc ^ (row&7);
  const int row2 = row + 32, oc2 = sc ^ (row2&7);
  const unsigned short* Kg0 = Kb + (size_t)row*KVD  + kvh*HD + oc*8;
  const unsigned short* Kg1 = Kb + (size_t)row2*KVD + kvh*HD + oc2*8;
  const unsigned short* Vg0 = Vt + (size_t)(kvh*HD+row)*SEQ  + oc*8;
  const unsigned short* Vg1 = Vt + (size_t)(kvh*HD+row2)*SEQ + oc2*8;

#define ATTN_STAGE(buf, kb_) { \
    const size_t koff = (size_t)(kb_)*64*KVD; const int voff = (kb_)*64; \
    gld_lds16(Kg0 + koff, &Ks[buf][tid*8]); \
    gld_lds16(Kg1 + koff, &Ks[buf][(tid+256)*8]); \
    gld_lds16(Vg0 + voff, &Vs[buf][tid*8]); \
    gld_lds16(Vg1 + voff, &Vs[buf][(tid+256)*8]); }

  ATTN_STAGE(0, 0);

  // Q fragments: 2 m-tiles x 2 k-chunks, straight from global
  short8 qa[2][2];
  {
    const unsigned short* qp0 = Qb + (size_t)(qb*128 + w*32 + l15)*ED + h*HD + l4*8;
    qa[0][0] = *(const short8*)qp0;
    qa[0][1] = *(const short8*)(qp0 + 32);
    const unsigned short* qp1 = qp0 + (size_t)16*ED;
    qa[1][0] = *(const short8*)qp1;
    qa[1][1] = *(const short8*)(qp1 + 32);
  }

  unsigned* Pw = &Psu[w][0];
  f32x4 o_acc[2][4] = {};
  float l_acc[2][4] = {{0.f,0.f,0.f,0.f},{0.f,0.f,0.f,0.f}};
  __syncthreads();

  for(int kb=0; kb<SEQ/64; kb++){
    const int cur = kb & 1;
    if (kb+1 < SEQ/64) ATTN_STAGE(cur^1, kb+1);

    __builtin_amdgcn_s_setprio(1);
    f32x4 s_acc[2][4] = {};
#pragma unroll
    for(int n=0;n<4;n++){
      int key = n*16 + l15;
#pragma unroll
      for(int ks=0;ks<2;ks++){
        short8 kf = *(const short8*)&Ks[cur][key*64 + (((ks*4+l4) ^ (key&7))*8)];
        s_acc[0][n] = __builtin_amdgcn_mfma_f32_16x16x32_bf16(qa[0][ks], kf, s_acc[0][n], 0,0,0);
        s_acc[1][n] = __builtin_amdgcn_mfma_f32_16x16x32_bf16(qa[1][ks], kf, s_acc[1][n], 0,0,0);
      }
    }
    __builtin_amdgcn_s_setprio(0);

    // softmax (no max-subtract; scale folded into Q): pack (key, key+16) pairs
#pragma unroll
    for(int mt=0;mt<2;mt++){
#pragma unroll
      for(int r=0;r<4;r++){
        float p0 = exp2f(s_acc[mt][0][r]), p1 = exp2f(s_acc[mt][1][r]);
        float p2 = exp2f(s_acc[mt][2][r]), p3 = exp2f(s_acc[mt][3][r]);
        l_acc[mt][r] += (p0+p1)+(p2+p3);
        unsigned u01, u23;
        asm("v_cvt_pk_bf16_f32 %0, %1, %2" : "=v"(u01) : "v"(p0), "v"(p1));
        asm("v_cvt_pk_bf16_f32 %0, %1, %2" : "=v"(u23) : "v"(p2), "v"(p3));
        const int q32 = mt*16 + l4*4 + r;
        Pw[q32*32 + (((l15>>2)     ^ (q32&7))<<2) + (l15&3)] = u01;
        Pw[q32*32 + (((4+(l15>>2)) ^ (q32&7))<<2) + (l15&3)] = u23;
      }
    }
    asm volatile("s_waitcnt lgkmcnt(0)" ::: "memory");

    __builtin_amdgcn_s_setprio(1);
#pragma unroll
    for(int ks=0;ks<2;ks++){
      short8 pa0 = *(const short8*)&Pw[(l15     )*32 + (((ks*4+l4) ^ (l15&7))<<2)];
      short8 pa1 = *(const short8*)&Pw[(16+l15  )*32 + (((ks*4+l4) ^ (l15&7))<<2)];
#pragma unroll
      for(int n=0;n<4;n++){
        int d = n*16 + l15;
        short8 vf = *(const short8*)&Vs[cur][d*64 + (((ks*4+l4) ^ (d&7))*8)];
        o_acc[0][n] = __builtin_amdgcn_mfma_f32_16x16x32_bf16(pa0, vf, o_acc[0][n], 0,0,0);
        o_acc[1][n] = __builtin_amdgcn_mfma_f32_16x16x32_bf16(pa1, vf, o_acc[1][n], 0,0,0);
      }
    }
    __builtin_amdgcn_s_setprio(0);
    __syncthreads();
  }
#undef ATTN_STAGE

  // epilogue
#pragma unroll
  for(int mt=0;mt<2;mt++)
#pragma unroll
    for(int r=0;r<4;r++){
      float t = l_acc[mt][r];
      t += __shfl_xor(t,1); t += __shfl_xor(t,2); t += __shfl_xor(t,4); t += __shfl_xor(t,8);
      l_acc[mt][r] = 1.0f / t;
    }
#pragma unroll
  for(int mt=0;mt<2;mt++)
#pragma unroll
    for(int n=0;n<4;n++){
      const int col = h*HD + n*16 + l15;
#pragma unroll
      for(int r=0;r<4;r++){
        const int srow = qb*128 + w*32 + mt*16 + l4*4 + r;
        Ob[(size_t)srow*ED + col] = f2bf(o_acc[mt][n][r] * l_acc[mt][r]);
      }
    }
}

extern "C" void kernel_launch(void* const* d_in, const int* in_sizes, int n_in,
                              void* d_out, int out_size, void* d_ws, size_t ws_size,
                              hipStream_t stream) {
  const float* Xq    = (const float*)d_in[0];
  const float* Xkv   = (const float*)d_in[1];
  const float* cos_q = (const float*)d_in[2];
  const float* sin_q = (const float*)d_in[3];
  const float* cos_k = (const float*)d_in[4];
  const float* sin_k = (const float*)d_in[5];
  const float* wq = (const float*)d_in[7];
  const float* wk = (const float*)d_in[8];
  const float* wv = (const float*)d_in[9];
  const float* wo = (const float*)d_in[10];
  float* out = (float*)d_out;

  char* ws = (char*)d_ws;
  const size_t MB = 1u<<20;
  unsigned short* Xb   = (unsigned short*)(ws + 0*MB);
  unsigned short* KVb  = (unsigned short*)(ws + 8*MB);
  unsigned short* Wqb  = (unsigned short*)(ws + 16*MB);
  unsigned short* WKVb = (unsigned short*)(ws + 24*MB);
  unsigned short* Wob  = (unsigned short*)(ws + 28*MB);
  unsigned short* Qb   = (unsigned short*)(ws + 36*MB);
  unsigned short* Kb   = (unsigned short*)(ws + 44*MB);
  unsigned short* Vtb  = (unsigned short*)(ws + 46*MB);
  unsigned short* Obf  = (unsigned short*)(ws + 48*MB);

  cvt_all<<<9216,256,0,stream>>>(Xq, Xkv, wq, wk, wv, wo, Xb, KVb, Wqb, WKVb, Wob);

  gemm_proj<<<384,256,0,stream>>>(Xb, Wqb, KVb, WKVb, Qb, Kb, Vtb);

  rope_all<<<2560,256,0,stream>>>(Qb, Kb, cos_q, sin_q, cos_k, sin_k);

  attn_k<<<dim3(SEQ/128, NHEADS),256,0,stream>>>(Qb, Kb, Vtb, Obf);

  gemm_out_k<<<256,256,0,stream>>>(Obf, Wob, out);
}